// Round 1
// baseline (148.761 us; speedup 1.0000x reference)
//
#include <hip/hip_runtime.h>
#include <hip/hip_bf16.h>
#include <cstdint>
#include <cstddef>

typedef __bf16 bf16_t;
typedef bf16_t bf16x8 __attribute__((ext_vector_type(8)));
typedef float f32x4 __attribute__((ext_vector_type(4)));
typedef unsigned short u16;
typedef u16 u16x4 __attribute__((ext_vector_type(4)));

#define S_LEN 2048
#define NB 2
#define NH 8
#define DHD 64
#define DM 512

static __device__ __forceinline__ u16 f2bf(float f) {
  union { float f; uint32_t u; } x; x.f = f;
  uint32_t r = x.u + 0x7FFFu + ((x.u >> 16) & 1u);   // RNE
  return (u16)(r >> 16);
}

// ---------------------------------------------------------------------------
// Projection: P = relu(X @ W^T + b) for X in {q,k,v}.
// Q,K written [B,H,S,64] bf16; V written transposed [B,H,64,S] bf16.
// 128x128 tile, BK=32, 4 waves (each wave a 64x64 quadrant, 4x4 16x16 frags).
// ---------------------------------------------------------------------------
__launch_bounds__(256)
__global__ void proj_kernel(const float* __restrict__ Xq,
                            const float* __restrict__ Xk,
                            const float* __restrict__ Xv,
                            const float* __restrict__ W,
                            const float* __restrict__ bias,
                            u16* __restrict__ Qw, u16* __restrict__ Kw,
                            u16* __restrict__ Vt) {
  __shared__ u16 As[128][40];   // row stride 80B = 16B-aligned
  __shared__ u16 Bs[128][40];
  const int z = blockIdx.z;
  const float* __restrict__ X = (z == 0) ? Xq : ((z == 1) ? Xk : Xv);
  const int m0 = blockIdx.x * 128;
  const int n0 = blockIdx.y * 128;
  const int t = threadIdx.x;
  const int lane = t & 63;
  const int wid = t >> 6;
  const int wr = wid >> 1, wc = wid & 1;
  const int fr = lane & 15, fg = lane >> 4;

  f32x4 acc[4][4] = {};

  const int srow = t >> 3;        // 0..31
  const int sc4 = (t & 7) * 4;    // 0,4,..,28

  for (int k0 = 0; k0 < DM; k0 += 32) {
    #pragma unroll
    for (int p = 0; p < 4; ++p) {
      int r = p * 32 + srow;
      float4 av = *reinterpret_cast<const float4*>(X + (size_t)(m0 + r) * DM + k0 + sc4);
      float4 bv = *reinterpret_cast<const float4*>(W + (size_t)(n0 + r) * DM + k0 + sc4);
      u16x4 a4, b4;
      a4[0] = f2bf(av.x); a4[1] = f2bf(av.y); a4[2] = f2bf(av.z); a4[3] = f2bf(av.w);
      b4[0] = f2bf(bv.x); b4[1] = f2bf(bv.y); b4[2] = f2bf(bv.z); b4[3] = f2bf(bv.w);
      *reinterpret_cast<u16x4*>(&As[r][sc4]) = a4;
      *reinterpret_cast<u16x4*>(&Bs[r][sc4]) = b4;
    }
    __syncthreads();
    bf16x8 af[4], bfr[4];
    #pragma unroll
    for (int mi = 0; mi < 4; ++mi)
      af[mi] = *reinterpret_cast<const bf16x8*>(&As[wr*64 + mi*16 + fr][fg*8]);
    #pragma unroll
    for (int ni = 0; ni < 4; ++ni)
      bfr[ni] = *reinterpret_cast<const bf16x8*>(&Bs[wc*64 + ni*16 + fr][fg*8]);
    #pragma unroll
    for (int mi = 0; mi < 4; ++mi)
      #pragma unroll
      for (int ni = 0; ni < 4; ++ni)
        acc[mi][ni] = __builtin_amdgcn_mfma_f32_16x16x32_bf16(af[mi], bfr[ni], acc[mi][ni], 0, 0, 0);
    __syncthreads();
  }

  // Epilogue: bias + ReLU, scatter to Q/K ([B,H,S,64]) or V^T ([B,H,64,S]).
  #pragma unroll
  for (int mi = 0; mi < 4; ++mi) {
    #pragma unroll
    for (int ni = 0; ni < 4; ++ni) {
      #pragma unroll
      for (int r = 0; r < 4; ++r) {
        int m = m0 + wr*64 + mi*16 + fg*4 + r;    // C/D: row=(lane>>4)*4+reg
        int e = n0 + wc*64 + ni*16 + fr;          // C/D: col=lane&15
        float v = acc[mi][ni][r] + bias[e];
        v = fmaxf(v, 0.0f);
        u16 bv = f2bf(v);
        int b = m >> 11, s = m & (S_LEN - 1);
        int h = e >> 6, dh = e & 63;
        size_t bh = (size_t)(b * NH + h);
        if (z == 0)      Qw[(bh * S_LEN + s) * DHD + dh] = bv;
        else if (z == 1) Kw[(bh * S_LEN + s) * DHD + dh] = bv;
        else             Vt[(bh * DHD + dh) * S_LEN + s] = bv;
      }
    }
  }
}

// ---------------------------------------------------------------------------
// Flash-style causal attention. 1 wave = one 16-row q-tile; KV-blocks of 32.
// Output permutation matches reference: out[((h*B+b)*S+s)*64+dh].
// ---------------------------------------------------------------------------
__launch_bounds__(256)
__global__ void attn_kernel(const u16* __restrict__ Qw, const u16* __restrict__ Kw,
                            const u16* __restrict__ Vt, float* __restrict__ out) {
  __shared__ u16 Pt[4][16][40];    // per-wave P tile, 16B-aligned rows
  const int t = threadIdx.x, lane = t & 63, wid = t >> 6;
  const int wg = blockIdx.x * 4 + wid;     // 0..2047
  const int bh = wg >> 7;                  // b*8 + h
  const int q0 = (wg & 127) * 16;
  const int fr = lane & 15, fg = lane >> 4;
  const u16* __restrict__ Qh = Qw + (size_t)bh * S_LEN * DHD;
  const u16* __restrict__ Kh = Kw + (size_t)bh * S_LEN * DHD;
  const u16* __restrict__ Vh = Vt + (size_t)bh * DHD * S_LEN;

  // Q fragments for A-operand: row = lane&15, k = (lane>>4)*8 (+32 per step)
  bf16x8 qf[2];
  #pragma unroll
  for (int st = 0; st < 2; ++st)
    qf[st] = *reinterpret_cast<const bf16x8*>(Qh + (size_t)(q0 + fr) * DHD + st*32 + fg*8);

  float m_run[4], l_run[4];
  f32x4 o[4] = {};
  #pragma unroll
  for (int r = 0; r < 4; ++r) { m_run[r] = -INFINITY; l_run[r] = 0.f; }

  const int kend = q0 + 16;
  for (int kb = 0; kb < kend; kb += 32) {
    // --- S = Q K^T (16 x 32), 4 MFMA ---
    f32x4 c[2] = {};
    #pragma unroll
    for (int fi = 0; fi < 2; ++fi)
      #pragma unroll
      for (int st = 0; st < 2; ++st) {
        bf16x8 kf = *reinterpret_cast<const bf16x8*>(
            Kh + (size_t)(kb + fi*16 + fr) * DHD + st*32 + fg*8);
        c[fi] = __builtin_amdgcn_mfma_f32_16x16x32_bf16(qf[st], kf, c[fi], 0, 0, 0);
      }

    // --- scale + causal mask ---
    float sv[2][4];
    #pragma unroll
    for (int fi = 0; fi < 2; ++fi)
      #pragma unroll
      for (int r = 0; r < 4; ++r) {
        int qg = q0 + fg*4 + r;
        int kg = kb + fi*16 + fr;
        float s = c[fi][r] * 0.125f;
        sv[fi][r] = (kg > qg) ? -INFINITY : s;
      }

    // --- online softmax (row-reduce across the 16-lane col groups) ---
    float pm[4];
    #pragma unroll
    for (int r = 0; r < 4; ++r) pm[r] = fmaxf(sv[0][r], sv[1][r]);
    #pragma unroll
    for (int off = 1; off < 16; off <<= 1)
      #pragma unroll
      for (int r = 0; r < 4; ++r)
        pm[r] = fmaxf(pm[r], __shfl_xor(pm[r], off));

    float alpha[4], rs[4];
    #pragma unroll
    for (int r = 0; r < 4; ++r) {
      float mn = fmaxf(m_run[r], pm[r]);     // pm=-inf (fully masked row) -> mn=m_run
      alpha[r] = __expf(m_run[r] - mn);      // first block: pm finite, so no NaN
      m_run[r] = mn;
      rs[r] = 0.f;
    }

    float pv[2][4];
    #pragma unroll
    for (int fi = 0; fi < 2; ++fi)
      #pragma unroll
      for (int r = 0; r < 4; ++r) {
        float p = __expf(sv[fi][r] - m_run[r]);   // exp(-inf - m) = 0
        pv[fi][r] = p;
        rs[r] += p;
      }
    #pragma unroll
    for (int off = 1; off < 16; off <<= 1)
      #pragma unroll
      for (int r = 0; r < 4; ++r)
        rs[r] += __shfl_xor(rs[r], off);
    #pragma unroll
    for (int r = 0; r < 4; ++r)
      l_run[r] = l_run[r] * alpha[r] + rs[r];
    #pragma unroll
    for (int ni = 0; ni < 4; ++ni)
      #pragma unroll
      for (int r = 0; r < 4; ++r)
        o[ni][r] *= alpha[r];

    // --- P -> LDS (C layout) then re-read as MFMA A-fragment ---
    #pragma unroll
    for (int fi = 0; fi < 2; ++fi)
      #pragma unroll
      for (int r = 0; r < 4; ++r)
        Pt[wid][fg*4 + r][fi*16 + fr] = f2bf(pv[fi][r]);
    asm volatile("s_waitcnt lgkmcnt(0)" ::: "memory");

    bf16x8 pf = *reinterpret_cast<const bf16x8*>(&Pt[wid][fr][fg*8]);
    #pragma unroll
    for (int ni = 0; ni < 4; ++ni) {
      bf16x8 vf = *reinterpret_cast<const bf16x8*>(
          Vh + (size_t)(ni*16 + fr) * S_LEN + kb + fg*8);
      o[ni] = __builtin_amdgcn_mfma_f32_16x16x32_bf16(pf, vf, o[ni], 0, 0, 0);
    }
  }

  // --- epilogue: divide by l, write with reference's permuted layout ---
  const int b = bh >> 3, h = bh & 7;
  #pragma unroll
  for (int ni = 0; ni < 4; ++ni)
    #pragma unroll
    for (int r = 0; r < 4; ++r) {
      int qg = q0 + fg*4 + r;
      int dh = ni*16 + fr;
      size_t idx = (((size_t)(h * NB + b)) * S_LEN + qg) * DHD + dh;
      out[idx] = o[ni][r] / l_run[r];
    }
}

extern "C" void kernel_launch(void* const* d_in, const int* in_sizes, int n_in,
                              void* d_out, int out_size, void* d_ws, size_t ws_size,
                              hipStream_t stream) {
  const float* q = (const float*)d_in[0];
  const float* k = (const float*)d_in[1];
  const float* v = (const float*)d_in[2];
  const float* W = (const float*)d_in[3];
  const float* b = (const float*)d_in[4];

  const size_t elems = (size_t)NB * NH * S_LEN * DHD;  // 2,097,152
  u16* Qw = (u16*)d_ws;
  u16* Kw = Qw + elems;
  u16* Vt = Kw + elems;

  dim3 gproj(4096 / 128, DM / 128, 3);
  proj_kernel<<<gproj, dim3(256), 0, stream>>>(q, k, v, W, b, Qw, Kw, Vt);

  const int nwaves = NB * NH * (S_LEN / 16);           // 2048
  attn_kernel<<<dim3(nwaves / 4), dim3(256), 0, stream>>>(Qw, Kw, Vt, (float*)d_out);
}

// Round 2
// 93.350 us; speedup vs baseline: 1.5936x; 1.5936x over previous
//
#include <hip/hip_runtime.h>
#include <hip/hip_bf16.h>
#include <cstdint>
#include <cstddef>

typedef __bf16 bf16_t;
typedef bf16_t bf16x8 __attribute__((ext_vector_type(8)));
typedef float f32x4 __attribute__((ext_vector_type(4)));
typedef unsigned short u16;
typedef u16 u16x4 __attribute__((ext_vector_type(4)));

#define S_LEN 2048
#define NB 2
#define NH 8
#define DHD 64
#define DM 512

static __device__ __forceinline__ u16 f2bf(float f) {
  union { float f; uint32_t u; } x; x.f = f;
  uint32_t r = x.u + 0x7FFFu + ((x.u >> 16) & 1u);   // RNE
  return (u16)(r >> 16);
}

static __device__ __forceinline__ uint32_t pkbf(float a, float b) {
  union { __bf16 h[2]; uint32_t u; } c;
  c.h[0] = (__bf16)a; c.h[1] = (__bf16)b;   // native cvt (compiler packs)
  return c.u;
}

// ---------------------------------------------------------------------------
// Projection: P = relu(X @ W^T + b) for X in {q,k,v}.
// Q pre-scaled by 1/8 (softmax scale folded in; relu commutes with pos scale).
// Q,K written [B,H,S,64] bf16; V written transposed [B,H,64,S] bf16.
// ---------------------------------------------------------------------------
__launch_bounds__(256)
__global__ void proj_kernel(const float* __restrict__ Xq,
                            const float* __restrict__ Xk,
                            const float* __restrict__ Xv,
                            const float* __restrict__ W,
                            const float* __restrict__ bias,
                            u16* __restrict__ Qw, u16* __restrict__ Kw,
                            u16* __restrict__ Vt) {
  __shared__ u16 As[128][40];
  __shared__ u16 Bs[128][40];
  const int z = blockIdx.z;
  const float* __restrict__ X = (z == 0) ? Xq : ((z == 1) ? Xk : Xv);
  const int m0 = blockIdx.x * 128;
  const int n0 = blockIdx.y * 128;
  const int t = threadIdx.x;
  const int lane = t & 63;
  const int wid = t >> 6;
  const int wr = wid >> 1, wc = wid & 1;
  const int fr = lane & 15, fg = lane >> 4;

  f32x4 acc[4][4] = {};

  const int srow = t >> 3;
  const int sc4 = (t & 7) * 4;

  for (int k0 = 0; k0 < DM; k0 += 32) {
    #pragma unroll
    for (int p = 0; p < 4; ++p) {
      int r = p * 32 + srow;
      float4 av = *reinterpret_cast<const float4*>(X + (size_t)(m0 + r) * DM + k0 + sc4);
      float4 bv = *reinterpret_cast<const float4*>(W + (size_t)(n0 + r) * DM + k0 + sc4);
      u16x4 a4, b4;
      a4[0] = f2bf(av.x); a4[1] = f2bf(av.y); a4[2] = f2bf(av.z); a4[3] = f2bf(av.w);
      b4[0] = f2bf(bv.x); b4[1] = f2bf(bv.y); b4[2] = f2bf(bv.z); b4[3] = f2bf(bv.w);
      *reinterpret_cast<u16x4*>(&As[r][sc4]) = a4;
      *reinterpret_cast<u16x4*>(&Bs[r][sc4]) = b4;
    }
    __syncthreads();
    bf16x8 af[4], bfr[4];
    #pragma unroll
    for (int mi = 0; mi < 4; ++mi)
      af[mi] = *reinterpret_cast<const bf16x8*>(&As[wr*64 + mi*16 + fr][fg*8]);
    #pragma unroll
    for (int ni = 0; ni < 4; ++ni)
      bfr[ni] = *reinterpret_cast<const bf16x8*>(&Bs[wc*64 + ni*16 + fr][fg*8]);
    #pragma unroll
    for (int mi = 0; mi < 4; ++mi)
      #pragma unroll
      for (int ni = 0; ni < 4; ++ni)
        acc[mi][ni] = __builtin_amdgcn_mfma_f32_16x16x32_bf16(af[mi], bfr[ni], acc[mi][ni], 0, 0, 0);
    __syncthreads();
  }

  #pragma unroll
  for (int mi = 0; mi < 4; ++mi) {
    #pragma unroll
    for (int ni = 0; ni < 4; ++ni) {
      #pragma unroll
      for (int r = 0; r < 4; ++r) {
        int m = m0 + wr*64 + mi*16 + fg*4 + r;
        int e = n0 + wc*64 + ni*16 + fr;
        float v = acc[mi][ni][r] + bias[e];
        if (z == 0) v *= 0.125f;          // fold 1/sqrt(Dh) into Q
        v = fmaxf(v, 0.0f);
        u16 bv = f2bf(v);
        int b = m >> 11, s = m & (S_LEN - 1);
        int h = e >> 6, dh = e & 63;
        size_t bh = (size_t)(b * NH + h);
        if (z == 0)      Qw[(bh * S_LEN + s) * DHD + dh] = bv;
        else if (z == 1) Kw[(bh * S_LEN + s) * DHD + dh] = bv;
        else             Vt[(bh * DHD + dh) * S_LEN + s] = bv;
      }
    }
  }
}

// ---------------------------------------------------------------------------
// Flash attention, swapped-QK^T formulation. 1 wave per block.
// Wave owns QBLK=32 rows; KV blocks of 32. S^T = mfma(K,Q): lane holds 8
// k-values for its q=fr row -> softmax reduce is local + 2 shfl hops.
// P packed to LDS (b64), re-read as PV A-frag; PV normal orientation.
// Only the final (diagonal) block applies the causal mask.
// ---------------------------------------------------------------------------
__launch_bounds__(64)
__global__ void attn_kernel(const u16* __restrict__ Qw, const u16* __restrict__ Kw,
                            const u16* __restrict__ Vt, float* __restrict__ out) {
  __shared__ u16 Pt[32][40];
  const int lane = threadIdx.x & 63;
  const int fr = lane & 15, fg = lane >> 4;
  const int bid = blockIdx.x;
  // XCD-grouped (2 heads per XCD), longest-tile-first dispatch
  const int xcd = bid & 7, j = bid >> 3;        // j in 0..127
  const int bh = 2 * xcd + (j & 1);
  const int tile = 63 - (j >> 1);
  const int q0 = tile * 32;

  const u16* __restrict__ Qh = Qw + (size_t)bh * S_LEN * DHD;
  const u16* __restrict__ Kh = Kw + (size_t)bh * S_LEN * DHD;
  const u16* __restrict__ Vh = Vt + (size_t)bh * DHD * S_LEN;

  // Q B-fragments (loop-invariant): col=q=fr, contraction d
  bf16x8 qf[2][2];
  #pragma unroll
  for (int qi = 0; qi < 2; ++qi)
    #pragma unroll
    for (int ds = 0; ds < 2; ++ds)
      qf[qi][ds] = *reinterpret_cast<const bf16x8*>(
          Qh + (size_t)(q0 + qi*16 + fr) * DHD + ds*32 + fg*8);

  f32x4 o[2][4] = {};                 // [qi][di], C-layout: row=q, col=d
  float m_s[2] = {-INFINITY, -INFINITY};
  float l_s[2] = {0.f, 0.f};

  bf16x8 kf[2][2];                    // K A-frags: row=k, contraction d
  auto loadK = [&](int kb) {
    #pragma unroll
    for (int ki = 0; ki < 2; ++ki)
      #pragma unroll
      for (int ds = 0; ds < 2; ++ds)
        kf[ki][ds] = *reinterpret_cast<const bf16x8*>(
            Kh + (size_t)(kb + ki*16 + fr) * DHD + ds*32 + fg*8);
  };
  loadK(0);                           // tile 0 -> diag block is kb=0 too

  const int base = (lane & 48) + ((lane & 48) >> 2);  // src lane base for C-layout xfer

  auto block_step = [&](int kb, bool masked, bool pref) {
    // --- S^T = K Q^T: D[k][q], 8 MFMA ---
    f32x4 s[2][2] = {};               // [ki][qi]
    #pragma unroll
    for (int ds = 0; ds < 2; ++ds)
      #pragma unroll
      for (int ki = 0; ki < 2; ++ki)
        #pragma unroll
        for (int qi = 0; qi < 2; ++qi)
          s[ki][qi] = __builtin_amdgcn_mfma_f32_16x16x32_bf16(kf[ki][ds], qf[qi][ds], s[ki][qi], 0, 0, 0);

    if (pref) loadK(kb + 32);         // prefetch next K block (hides under softmax)

    bf16x8 vf[4];                     // V B-frags: col=d, contraction k
    #pragma unroll
    for (int di = 0; di < 4; ++di)
      vf[di] = *reinterpret_cast<const bf16x8*>(
          Vh + (size_t)(di*16 + fr) * S_LEN + kb + fg*8);

    // --- mask (diag only) ---
    float p[2][2][4];
    #pragma unroll
    for (int ki = 0; ki < 2; ++ki)
      #pragma unroll
      for (int qi = 0; qi < 2; ++qi)
        #pragma unroll
        for (int r = 0; r < 4; ++r) {
          float v = s[ki][qi][r];
          if (masked) {
            int kl = ki*16 + fg*4 + r, ql = qi*16 + fr;
            v = (kl > ql) ? -INFINITY : v;
          }
          p[ki][qi][r] = v;
        }

    // --- row max: 7 local fmax + 2 shfl hops per qi ---
    float pm[2];
    #pragma unroll
    for (int qi = 0; qi < 2; ++qi) {
      float a = fmaxf(fmaxf(p[0][qi][0], p[0][qi][1]), fmaxf(p[0][qi][2], p[0][qi][3]));
      float b = fmaxf(fmaxf(p[1][qi][0], p[1][qi][1]), fmaxf(p[1][qi][2], p[1][qi][3]));
      float m = fmaxf(a, b);
      m = fmaxf(m, __shfl_xor(m, 16));
      m = fmaxf(m, __shfl_xor(m, 32));
      pm[qi] = m;
    }

    // --- online max update (skipped when no row max grows: T13-style) ---
    float mn[2];
    bool upd = false;
    #pragma unroll
    for (int qi = 0; qi < 2; ++qi) {
      mn[qi] = fmaxf(m_s[qi], pm[qi]);
      upd = upd || (pm[qi] > m_s[qi]);
    }
    if (__any(upd)) {
      float al[2];
      #pragma unroll
      for (int qi = 0; qi < 2; ++qi) {
        al[qi] = __expf(m_s[qi] - mn[qi]);
        m_s[qi] = mn[qi];
        l_s[qi] *= al[qi];
      }
      #pragma unroll
      for (int rr = 0; rr < 4; ++rr) {
        float a0 = __shfl(al[0], base + rr);
        float a1 = __shfl(al[1], base + rr);
        #pragma unroll
        for (int di = 0; di < 4; ++di) { o[0][di][rr] *= a0; o[1][di][rr] *= a1; }
      }
    }

    // --- P = exp(S - m), row sums ---
    float rs[2] = {0.f, 0.f};
    #pragma unroll
    for (int ki = 0; ki < 2; ++ki)
      #pragma unroll
      for (int qi = 0; qi < 2; ++qi)
        #pragma unroll
        for (int r = 0; r < 4; ++r) {
          float e = __expf(p[ki][qi][r] - m_s[qi]);
          p[ki][qi][r] = e;
          rs[qi] += e;
        }
    #pragma unroll
    for (int qi = 0; qi < 2; ++qi) {
      float r2 = rs[qi];
      r2 += __shfl_xor(r2, 16);
      r2 += __shfl_xor(r2, 32);
      l_s[qi] += r2;
    }

    // --- pack P -> LDS (b64 per (qi,ki)), re-read as PV A-frag ---
    #pragma unroll
    for (int qi = 0; qi < 2; ++qi)
      #pragma unroll
      for (int ki = 0; ki < 2; ++ki) {
        uint2 w;
        w.x = pkbf(p[ki][qi][0], p[ki][qi][1]);
        w.y = pkbf(p[ki][qi][2], p[ki][qi][3]);
        *reinterpret_cast<uint2*>(&Pt[qi*16 + fr][ki*16 + fg*4]) = w;
      }
    asm volatile("s_waitcnt lgkmcnt(0)" ::: "memory");
    bf16x8 pf[2];
    #pragma unroll
    for (int qi = 0; qi < 2; ++qi)
      pf[qi] = *reinterpret_cast<const bf16x8*>(&Pt[qi*16 + fr][fg*8]);

    #pragma unroll
    for (int qi = 0; qi < 2; ++qi)
      #pragma unroll
      for (int di = 0; di < 4; ++di)
        o[qi][di] = __builtin_amdgcn_mfma_f32_16x16x32_bf16(pf[qi], vf[di], o[qi][di], 0, 0, 0);
  };

  const int nmain = tile;             // full (unmasked) 32-blocks
  for (int it = 0; it < nmain; ++it)
    block_step(it * 32, false, true);
  block_step(q0, true, false);        // diagonal block

  // --- epilogue: l to C-layout, normalize, write permuted output ---
  const int b = bh >> 3, h = bh & 7;
  #pragma unroll
  for (int rr = 0; rr < 4; ++rr) {
    float l0 = __shfl(l_s[0], base + rr);
    float l1 = __shfl(l_s[1], base + rr);
    float i0 = 1.0f / l0, i1 = 1.0f / l1;
    int qa = q0 + fg*4 + rr;
    int qb2 = qa + 16;
    #pragma unroll
    for (int di = 0; di < 4; ++di) {
      int dh = di*16 + fr;
      out[(((size_t)(h * NB + b)) * S_LEN + qa) * DHD + dh] = o[0][di][rr] * i0;
      out[(((size_t)(h * NB + b)) * S_LEN + qb2) * DHD + dh] = o[1][di][rr] * i1;
    }
  }
}

extern "C" void kernel_launch(void* const* d_in, const int* in_sizes, int n_in,
                              void* d_out, int out_size, void* d_ws, size_t ws_size,
                              hipStream_t stream) {
  const float* q = (const float*)d_in[0];
  const float* k = (const float*)d_in[1];
  const float* v = (const float*)d_in[2];
  const float* W = (const float*)d_in[3];
  const float* b = (const float*)d_in[4];

  const size_t elems = (size_t)NB * NH * S_LEN * DHD;
  u16* Qw = (u16*)d_ws;
  u16* Kw = Qw + elems;
  u16* Vt = Kw + elems;

  dim3 gproj(4096 / 128, DM / 128, 3);
  proj_kernel<<<gproj, dim3(256), 0, stream>>>(q, k, v, W, b, Qw, Kw, Vt);

  const int nblocks = NB * NH * (S_LEN / 32);   // 1024 single-wave blocks
  attn_kernel<<<dim3(nblocks), dim3(64), 0, stream>>>(Qw, Kw, Vt, (float*)d_out);
}

// Round 3
// 92.128 us; speedup vs baseline: 1.6147x; 1.0133x over previous
//
#include <hip/hip_runtime.h>
#include <hip/hip_bf16.h>
#include <cstdint>
#include <cstddef>

typedef __bf16 bf16_t;
typedef bf16_t bf16x8 __attribute__((ext_vector_type(8)));
typedef float f32x4 __attribute__((ext_vector_type(4)));
typedef unsigned short u16;
typedef u16 u16x4 __attribute__((ext_vector_type(4)));

#define S_LEN 2048
#define NB 2
#define NH 8
#define DHD 64
#define DM 512

static __device__ __forceinline__ u16 bfbits(float f) {
  union { __bf16 h; u16 u; } c; c.h = (__bf16)f; return c.u;
}
static __device__ __forceinline__ float bits2f(u16 b) {
  union { u16 u; __bf16 h; } c; c.u = b; return (float)c.h;
}
static __device__ __forceinline__ uint32_t pkbf(float a, float b) {
  union { __bf16 h[2]; uint32_t u; } c;
  c.h[0] = (__bf16)a; c.h[1] = (__bf16)b;
  return c.u;
}

// ---------------------------------------------------------------------------
// Projection: P = relu(X @ W^T + b). Q pre-scaled by 1/8.
// Q,K -> [B,H,S,64] bf16; V -> transposed [B,H,64,S] bf16.
// 1-D grid, XCD-swizzled: xcd=bid&7 owns 4 m-panels; n-blocks innermost so
// concurrent same-panel blocks share the A fetch in that XCD's L2.
// ---------------------------------------------------------------------------
__launch_bounds__(256)
__global__ void proj_kernel(const float* __restrict__ Xq,
                            const float* __restrict__ Xk,
                            const float* __restrict__ Xv,
                            const float* __restrict__ W,
                            const float* __restrict__ bias,
                            u16* __restrict__ Qw, u16* __restrict__ Kw,
                            u16* __restrict__ Vt) {
  __shared__ u16 As[128][40];
  __shared__ u16 Bs[128][40];
  const int bid = blockIdx.x;
  const int xcd = bid & 7;
  const int u = bid >> 3;               // 0..47
  const int n0 = (u & 3) * 128;
  const int mi = (u >> 2) & 3;
  const int z = u >> 4;                 // 0..2
  const int m0 = (xcd * 4 + mi) * 128;
  const float* __restrict__ X = (z == 0) ? Xq : ((z == 1) ? Xk : Xv);

  const int t = threadIdx.x;
  const int lane = t & 63;
  const int wid = t >> 6;
  const int wr = wid >> 1, wc = wid & 1;
  const int fr = lane & 15, fg = lane >> 4;

  f32x4 acc[4][4] = {};

  const int srow = t >> 3;
  const int sc4 = (t & 7) * 4;

  for (int k0 = 0; k0 < DM; k0 += 32) {
    #pragma unroll
    for (int p = 0; p < 4; ++p) {
      int r = p * 32 + srow;
      float4 av = *reinterpret_cast<const float4*>(X + (size_t)(m0 + r) * DM + k0 + sc4);
      float4 bv = *reinterpret_cast<const float4*>(W + (size_t)(n0 + r) * DM + k0 + sc4);
      u16x4 a4, b4;
      a4[0] = bfbits(av.x); a4[1] = bfbits(av.y); a4[2] = bfbits(av.z); a4[3] = bfbits(av.w);
      b4[0] = bfbits(bv.x); b4[1] = bfbits(bv.y); b4[2] = bfbits(bv.z); b4[3] = bfbits(bv.w);
      *reinterpret_cast<u16x4*>(&As[r][sc4]) = a4;
      *reinterpret_cast<u16x4*>(&Bs[r][sc4]) = b4;
    }
    __syncthreads();
    bf16x8 af[4], bfr[4];
    #pragma unroll
    for (int mi2 = 0; mi2 < 4; ++mi2)
      af[mi2] = *reinterpret_cast<const bf16x8*>(&As[wr*64 + mi2*16 + fr][fg*8]);
    #pragma unroll
    for (int ni = 0; ni < 4; ++ni)
      bfr[ni] = *reinterpret_cast<const bf16x8*>(&Bs[wc*64 + ni*16 + fr][fg*8]);
    #pragma unroll
    for (int mi2 = 0; mi2 < 4; ++mi2)
      #pragma unroll
      for (int ni = 0; ni < 4; ++ni)
        acc[mi2][ni] = __builtin_amdgcn_mfma_f32_16x16x32_bf16(af[mi2], bfr[ni], acc[mi2][ni], 0, 0, 0);
    __syncthreads();
  }

  #pragma unroll
  for (int mi2 = 0; mi2 < 4; ++mi2) {
    #pragma unroll
    for (int ni = 0; ni < 4; ++ni) {
      #pragma unroll
      for (int r = 0; r < 4; ++r) {
        int m = m0 + wr*64 + mi2*16 + fg*4 + r;
        int e = n0 + wc*64 + ni*16 + fr;
        float v = acc[mi2][ni][r] + bias[e];
        if (z == 0) v *= 0.125f;          // fold 1/sqrt(Dh) into Q
        v = fmaxf(v, 0.0f);
        u16 bv = bfbits(v);
        int b = m >> 11, s = m & (S_LEN - 1);
        int h = e >> 6, dh = e & 63;
        size_t bh = (size_t)(b * NH + h);
        if (z == 0)      Qw[(bh * S_LEN + s) * DHD + dh] = bv;
        else if (z == 1) Kw[(bh * S_LEN + s) * DHD + dh] = bv;
        else             Vt[(bh * DHD + dh) * S_LEN + s] = bv;
      }
    }
  }
}

// ---------------------------------------------------------------------------
// Split-K flash attention (swapped QK^T). 1 wave/block, QBLK=32 q-rows,
// KV chunk = 512 rows (<=16 steps of 32). Single-chunk tiles (t<16) write
// out directly; others write (O bf16, m, l) partials for reduce_kernel.
// ---------------------------------------------------------------------------
__launch_bounds__(64)
__global__ void attn_kernel(const u16* __restrict__ Qw, const u16* __restrict__ Kw,
                            const u16* __restrict__ Vt, u16* __restrict__ Opart,
                            float* __restrict__ mlbuf, float* __restrict__ out) {
  __shared__ u16 Pt[32][40];
  const int bid = blockIdx.x;
  const int bh = bid & 15;              // xcd = bid&7 -> 2 heads per XCD
  const int w = bid >> 4;               // 0..255
  const int tile = w >> 2;              // 0..63
  const int chunk = w & 3;
  const int nc = (tile >> 4) + 1;       // chunks for this tile (1..4)
  if (chunk >= nc) return;
  const int s0 = chunk * 16;
  const int s1e = s0 + 16;
  const int s1 = (s1e < tile + 1) ? s1e : (tile + 1);
  const int q0 = tile * 32;

  const int lane = threadIdx.x & 63;
  const int fr = lane & 15, fg = lane >> 4;

  const u16* __restrict__ Qh = Qw + (size_t)bh * S_LEN * DHD;
  const u16* __restrict__ Kh = Kw + (size_t)bh * S_LEN * DHD;
  const u16* __restrict__ Vh = Vt + (size_t)bh * DHD * S_LEN;

  bf16x8 qf[2][2];
  #pragma unroll
  for (int qi = 0; qi < 2; ++qi)
    #pragma unroll
    for (int ds = 0; ds < 2; ++ds)
      qf[qi][ds] = *reinterpret_cast<const bf16x8*>(
          Qh + (size_t)(q0 + qi*16 + fr) * DHD + ds*32 + fg*8);

  f32x4 o[2][4] = {};
  float m_s[2] = {-INFINITY, -INFINITY};
  float l_s[2] = {0.f, 0.f};

  bf16x8 kf[2][2];
  auto loadK = [&](int kb) {
    #pragma unroll
    for (int ki = 0; ki < 2; ++ki)
      #pragma unroll
      for (int ds = 0; ds < 2; ++ds)
        kf[ki][ds] = *reinterpret_cast<const bf16x8*>(
            Kh + (size_t)(kb + ki*16 + fr) * DHD + ds*32 + fg*8);
  };
  loadK(s0 * 32);

  const int base = (lane & 48) + ((lane & 48) >> 2);

  auto block_step = [&](int kb, bool masked, bool pref) {
    f32x4 s[2][2] = {};
    #pragma unroll
    for (int ds = 0; ds < 2; ++ds)
      #pragma unroll
      for (int ki = 0; ki < 2; ++ki)
        #pragma unroll
        for (int qi = 0; qi < 2; ++qi)
          s[ki][qi] = __builtin_amdgcn_mfma_f32_16x16x32_bf16(kf[ki][ds], qf[qi][ds], s[ki][qi], 0, 0, 0);

    if (pref) loadK(kb + 32);

    bf16x8 vf[4];
    #pragma unroll
    for (int di = 0; di < 4; ++di)
      vf[di] = *reinterpret_cast<const bf16x8*>(
          Vh + (size_t)(di*16 + fr) * S_LEN + kb + fg*8);

    float p[2][2][4];
    #pragma unroll
    for (int ki = 0; ki < 2; ++ki)
      #pragma unroll
      for (int qi = 0; qi < 2; ++qi)
        #pragma unroll
        for (int r = 0; r < 4; ++r) {
          float v = s[ki][qi][r];
          if (masked) {
            int kl = ki*16 + fg*4 + r, ql = qi*16 + fr;
            v = (kl > ql) ? -INFINITY : v;
          }
          p[ki][qi][r] = v;
        }

    float pm[2];
    #pragma unroll
    for (int qi = 0; qi < 2; ++qi) {
      float a = fmaxf(fmaxf(p[0][qi][0], p[0][qi][1]), fmaxf(p[0][qi][2], p[0][qi][3]));
      float b = fmaxf(fmaxf(p[1][qi][0], p[1][qi][1]), fmaxf(p[1][qi][2], p[1][qi][3]));
      float m = fmaxf(a, b);
      m = fmaxf(m, __shfl_xor(m, 16));
      m = fmaxf(m, __shfl_xor(m, 32));
      pm[qi] = m;
    }

    float mn[2];
    bool upd = false;
    #pragma unroll
    for (int qi = 0; qi < 2; ++qi) {
      mn[qi] = fmaxf(m_s[qi], pm[qi]);
      upd = upd || (pm[qi] > m_s[qi]);
    }
    if (__any(upd)) {
      float al[2];
      #pragma unroll
      for (int qi = 0; qi < 2; ++qi) {
        al[qi] = __expf(m_s[qi] - mn[qi]);
        m_s[qi] = mn[qi];
        l_s[qi] *= al[qi];
      }
      #pragma unroll
      for (int rr = 0; rr < 4; ++rr) {
        float a0 = __shfl(al[0], base + rr);
        float a1 = __shfl(al[1], base + rr);
        #pragma unroll
        for (int di = 0; di < 4; ++di) { o[0][di][rr] *= a0; o[1][di][rr] *= a1; }
      }
    }

    float rs[2] = {0.f, 0.f};
    #pragma unroll
    for (int ki = 0; ki < 2; ++ki)
      #pragma unroll
      for (int qi = 0; qi < 2; ++qi)
        #pragma unroll
        for (int r = 0; r < 4; ++r) {
          float e = __expf(p[ki][qi][r] - m_s[qi]);
          p[ki][qi][r] = e;
          rs[qi] += e;
        }
    #pragma unroll
    for (int qi = 0; qi < 2; ++qi) {
      float r2 = rs[qi];
      r2 += __shfl_xor(r2, 16);
      r2 += __shfl_xor(r2, 32);
      l_s[qi] += r2;
    }

    #pragma unroll
    for (int qi = 0; qi < 2; ++qi)
      #pragma unroll
      for (int ki = 0; ki < 2; ++ki) {
        uint2 wv;
        wv.x = pkbf(p[ki][qi][0], p[ki][qi][1]);
        wv.y = pkbf(p[ki][qi][2], p[ki][qi][3]);
        *reinterpret_cast<uint2*>(&Pt[qi*16 + fr][ki*16 + fg*4]) = wv;
      }
    asm volatile("s_waitcnt lgkmcnt(0)" ::: "memory");
    bf16x8 pf[2];
    #pragma unroll
    for (int qi = 0; qi < 2; ++qi)
      pf[qi] = *reinterpret_cast<const bf16x8*>(&Pt[qi*16 + fr][fg*8]);

    #pragma unroll
    for (int qi = 0; qi < 2; ++qi)
      #pragma unroll
      for (int di = 0; di < 4; ++di)
        o[qi][di] = __builtin_amdgcn_mfma_f32_16x16x32_bf16(pf[qi], vf[di], o[qi][di], 0, 0, 0);
  };

  for (int s = s0; s < s1; ++s)
    block_step(s * 32, s == tile, s + 1 < s1);

  if (nc == 1) {
    // direct write (tiles 0..15)
    const int b = bh >> 3, h = bh & 7;
    #pragma unroll
    for (int rr = 0; rr < 4; ++rr) {
      float l0 = __shfl(l_s[0], base + rr);
      float l1 = __shfl(l_s[1], base + rr);
      float i0 = 1.0f / l0, i1 = 1.0f / l1;
      int qa = q0 + fg*4 + rr;
      int qb2 = qa + 16;
      #pragma unroll
      for (int di = 0; di < 4; ++di) {
        int dh = di*16 + fr;
        out[(((size_t)(h * NB + b)) * S_LEN + qa) * DHD + dh] = o[0][di][rr] * i0;
        out[(((size_t)(h * NB + b)) * S_LEN + qb2) * DHD + dh] = o[1][di][rr] * i1;
      }
    }
  } else {
    // partial write: O (bf16, per-lane contiguous), m/l (f32)
    const size_t slot = ((size_t)(bh * 64 + tile)) * 4 + chunk;
    u16* op = Opart + slot * 2048 + (size_t)lane * 32;
    #pragma unroll
    for (int qi = 0; qi < 2; ++qi)
      #pragma unroll
      for (int di = 0; di < 4; ++di) {
        u16x4 v4;
        #pragma unroll
        for (int r = 0; r < 4; ++r) v4[r] = bfbits(o[qi][di][r]);
        *reinterpret_cast<u16x4*>(op + qi*16 + di*4) = v4;
      }
    if (fg == 0) {
      float* mlp = mlbuf + slot * 64;
      #pragma unroll
      for (int qi = 0; qi < 2; ++qi) {
        mlp[qi*16 + fr] = m_s[qi];
        mlp[32 + qi*16 + fr] = l_s[qi];
      }
    }
  }
}

// ---------------------------------------------------------------------------
// Combine split-K partials for tiles 16..63. One wave per (bh, tile).
// ---------------------------------------------------------------------------
__launch_bounds__(64)
__global__ void reduce_kernel(const u16* __restrict__ Opart,
                              const float* __restrict__ mlbuf,
                              float* __restrict__ out) {
  const int bid = blockIdx.x;           // 0..767
  const int bh = bid & 15;
  const int tile = 16 + (bid >> 4);
  const int nc = (tile >> 4) + 1;       // 2..4
  const int lane = threadIdx.x & 63;
  const int fr = lane & 15, fg = lane >> 4;

  float M[2][4], L[2][4];
  f32x4 O[2][4] = {};
  #pragma unroll
  for (int qi = 0; qi < 2; ++qi)
    #pragma unroll
    for (int r = 0; r < 4; ++r) { M[qi][r] = -INFINITY; L[qi][r] = 0.f; }

  const size_t slot0 = ((size_t)(bh * 64 + tile)) * 4;
  for (int c = 0; c < nc; ++c) {
    const float* mlp = mlbuf + (slot0 + c) * 64;
    const u16* op = Opart + (slot0 + c) * 2048 + (size_t)lane * 32;
    u16x4 ov[2][4];
    #pragma unroll
    for (int qi = 0; qi < 2; ++qi)
      #pragma unroll
      for (int di = 0; di < 4; ++di)
        ov[qi][di] = *reinterpret_cast<const u16x4*>(op + qi*16 + di*4);
    #pragma unroll
    for (int qi = 0; qi < 2; ++qi)
      #pragma unroll
      for (int r = 0; r < 4; ++r) {
        float mc = mlp[qi*16 + fg*4 + r];
        float lc = mlp[32 + qi*16 + fg*4 + r];
        float Mn = fmaxf(M[qi][r], mc);
        float wo = __expf(M[qi][r] - Mn);
        float wc = __expf(mc - Mn);
        M[qi][r] = Mn;
        L[qi][r] = L[qi][r] * wo + wc * lc;
        #pragma unroll
        for (int di = 0; di < 4; ++di)
          O[qi][di][r] = O[qi][di][r] * wo + wc * bits2f(ov[qi][di][r]);
      }
  }

  const int b = bh >> 3, h = bh & 7;
  #pragma unroll
  for (int qi = 0; qi < 2; ++qi)
    #pragma unroll
    for (int r = 0; r < 4; ++r) {
      float inv = 1.0f / L[qi][r];
      int q = tile*32 + qi*16 + fg*4 + r;
      #pragma unroll
      for (int di = 0; di < 4; ++di)
        out[(((size_t)(h * NB + b)) * S_LEN + q) * DHD + di*16 + fr] = O[qi][di][r] * inv;
    }
}

extern "C" void kernel_launch(void* const* d_in, const int* in_sizes, int n_in,
                              void* d_out, int out_size, void* d_ws, size_t ws_size,
                              hipStream_t stream) {
  const float* q = (const float*)d_in[0];
  const float* k = (const float*)d_in[1];
  const float* v = (const float*)d_in[2];
  const float* W = (const float*)d_in[3];
  const float* b = (const float*)d_in[4];

  const size_t elems = (size_t)NB * NH * S_LEN * DHD;  // 2,097,152
  u16* Qw = (u16*)d_ws;
  u16* Kw = Qw + elems;
  u16* Vt = Kw + elems;
  u16* Opart = Vt + elems;                      // 4096 slots * 2048 u16 = 16 MiB
  float* mlbuf = (float*)(Opart + (size_t)4096 * 2048);  // 1 MiB

  proj_kernel<<<dim3(384), dim3(256), 0, stream>>>(q, k, v, W, b, Qw, Kw, Vt);

  attn_kernel<<<dim3(4096), dim3(64), 0, stream>>>(Qw, Kw, Vt, Opart, mlbuf, (float*)d_out);

  reduce_kernel<<<dim3(768), dim3(64), 0, stream>>>(Opart, mlbuf, (float*)d_out);
}

// Round 4
// 85.609 us; speedup vs baseline: 1.7377x; 1.0762x over previous
//
#include <hip/hip_runtime.h>
#include <hip/hip_bf16.h>
#include <cstdint>
#include <cstddef>

typedef __bf16 bf16_t;
typedef bf16_t bf16x8 __attribute__((ext_vector_type(8)));
typedef float f32x4 __attribute__((ext_vector_type(4)));
typedef unsigned short u16;
typedef u16 u16x4 __attribute__((ext_vector_type(4)));
typedef u16 u16x8 __attribute__((ext_vector_type(8)));

#define S_LEN 2048
#define NB 2
#define NH 8
#define DHD 64
#define DM 512

static __device__ __forceinline__ u16 bfbits(float f) {
  union { __bf16 h; u16 u; } c; c.h = (__bf16)f; return c.u;
}
static __device__ __forceinline__ float bits2f(u16 b) {
  union { u16 u; __bf16 h; } c; c.u = b; return (float)c.h;
}
static __device__ __forceinline__ uint32_t pkbf(float a, float b) {
  union { __bf16 h[2]; uint32_t u; } c;
  c.h[0] = (__bf16)a; c.h[1] = (__bf16)b;
  return c.u;
}

// ---------------------------------------------------------------------------
// fp32 -> bf16 convert pass (BW-bound). z picks {q,k,v,W}.
// ---------------------------------------------------------------------------
__launch_bounds__(256)
__global__ void cvt_kernel(const float* __restrict__ q, const float* __restrict__ k,
                           const float* __restrict__ v, const float* __restrict__ W,
                           u16* __restrict__ dst) {
  const int z = blockIdx.y;
  if (z == 3 && blockIdx.x >= 128) return;
  const float* __restrict__ src = (z == 0) ? q : (z == 1) ? k : (z == 2) ? v : W;
  u16* __restrict__ d = dst + (size_t)z * 2097152;
  size_t i = ((size_t)blockIdx.x * 256 + threadIdx.x) * 8;
  float4 a = *reinterpret_cast<const float4*>(src + i);
  float4 b = *reinterpret_cast<const float4*>(src + i + 4);
  u16x8 r;
  r[0] = bfbits(a.x); r[1] = bfbits(a.y); r[2] = bfbits(a.z); r[3] = bfbits(a.w);
  r[4] = bfbits(b.x); r[5] = bfbits(b.y); r[6] = bfbits(b.z); r[7] = bfbits(b.w);
  *reinterpret_cast<u16x8*>(d + i) = r;
}

// ---------------------------------------------------------------------------
// Projection GEMM (bf16 in): P = relu(X @ W^T + b). Q pre-scaled by 1/8.
// Q,K -> [B,H,S,64] bf16; V -> transposed [B,H,64,S] bf16. XCD-swizzled grid.
// ---------------------------------------------------------------------------
__launch_bounds__(256)
__global__ void proj_kernel(const u16* __restrict__ Xall, const u16* __restrict__ Wb,
                            const float* __restrict__ bias,
                            u16* __restrict__ Qw, u16* __restrict__ Kw,
                            u16* __restrict__ Vt) {
  __shared__ u16 As[128][40];
  __shared__ u16 Bs[128][40];
  const int bid = blockIdx.x;
  const int xcd = bid & 7;
  const int u = bid >> 3;               // 0..47
  const int n0 = (u & 3) * 128;
  const int mi = (u >> 2) & 3;
  const int z = u >> 4;                 // 0..2
  const int m0 = (xcd * 4 + mi) * 128;
  const u16* __restrict__ X = Xall + (size_t)z * 2097152;

  const int t = threadIdx.x;
  const int lane = t & 63;
  const int wid = t >> 6;
  const int wr = wid >> 1, wc = wid & 1;
  const int fr = lane & 15, fg = lane >> 4;

  f32x4 acc[4][4] = {};

  for (int k0 = 0; k0 < DM; k0 += 32) {
    #pragma unroll
    for (int h = 0; h < 2; ++h) {
      int c = t + h * 256;
      int r = c >> 2, col = (c & 3) * 8;
      *reinterpret_cast<uint4*>(&As[r][col]) =
          *reinterpret_cast<const uint4*>(X + (size_t)(m0 + r) * DM + k0 + col);
      *reinterpret_cast<uint4*>(&Bs[r][col]) =
          *reinterpret_cast<const uint4*>(Wb + (size_t)(n0 + r) * DM + k0 + col);
    }
    __syncthreads();
    bf16x8 af[4], bfr[4];
    #pragma unroll
    for (int mi2 = 0; mi2 < 4; ++mi2)
      af[mi2] = *reinterpret_cast<const bf16x8*>(&As[wr*64 + mi2*16 + fr][fg*8]);
    #pragma unroll
    for (int ni = 0; ni < 4; ++ni)
      bfr[ni] = *reinterpret_cast<const bf16x8*>(&Bs[wc*64 + ni*16 + fr][fg*8]);
    __builtin_amdgcn_s_setprio(1);
    #pragma unroll
    for (int mi2 = 0; mi2 < 4; ++mi2)
      #pragma unroll
      for (int ni = 0; ni < 4; ++ni)
        acc[mi2][ni] = __builtin_amdgcn_mfma_f32_16x16x32_bf16(af[mi2], bfr[ni], acc[mi2][ni], 0, 0, 0);
    __builtin_amdgcn_s_setprio(0);
    __syncthreads();
  }

  #pragma unroll
  for (int mi2 = 0; mi2 < 4; ++mi2) {
    #pragma unroll
    for (int ni = 0; ni < 4; ++ni) {
      #pragma unroll
      for (int r = 0; r < 4; ++r) {
        int m = m0 + wr*64 + mi2*16 + fg*4 + r;
        int e = n0 + wc*64 + ni*16 + fr;
        float v = acc[mi2][ni][r] + bias[e];
        if (z == 0) v *= 0.125f;          // fold 1/sqrt(Dh) into Q
        v = fmaxf(v, 0.0f);
        u16 bv = bfbits(v);
        int b = m >> 11, s = m & (S_LEN - 1);
        int h = e >> 6, dh = e & 63;
        size_t bh = (size_t)(b * NH + h);
        if (z == 0)      Qw[(bh * S_LEN + s) * DHD + dh] = bv;
        else if (z == 1) Kw[(bh * S_LEN + s) * DHD + dh] = bv;
        else             Vt[(bh * DHD + dh) * S_LEN + s] = bv;
      }
    }
  }
}

// ---------------------------------------------------------------------------
// Split-K flash attention, UNNORMALIZED softmax (scores >= 0 and small since
// Q,K are post-ReLU: no running max, no rescale; l deferred to end-of-kernel
// lane reduce). 1 wave/block, QBLK=32, KV chunk = 512 rows.
// ---------------------------------------------------------------------------
__launch_bounds__(64)
__global__ void attn_kernel(const u16* __restrict__ Qw, const u16* __restrict__ Kw,
                            const u16* __restrict__ Vt, u16* __restrict__ Opart,
                            float* __restrict__ lbuf, float* __restrict__ out) {
  __shared__ u16 Pt[32][40];
  const int bid = blockIdx.x;
  const int bh = bid & 15;              // xcd = bid&7 -> 2 heads per XCD
  const int w = bid >> 4;               // 0..255
  const int tile = w >> 2;              // 0..63
  const int chunk = w & 3;
  const int nc = (tile >> 4) + 1;       // chunks for this tile (1..4)
  if (chunk >= nc) return;
  const int s0 = chunk * 16;
  const int s1e = s0 + 16;
  const int s1 = (s1e < tile + 1) ? s1e : (tile + 1);
  const int q0 = tile * 32;

  const int lane = threadIdx.x & 63;
  const int fr = lane & 15, fg = lane >> 4;

  const u16* __restrict__ Qh = Qw + (size_t)bh * S_LEN * DHD;
  const u16* __restrict__ Kh = Kw + (size_t)bh * S_LEN * DHD;
  const u16* __restrict__ Vh = Vt + (size_t)bh * DHD * S_LEN;

  bf16x8 qf[2][2];
  #pragma unroll
  for (int qi = 0; qi < 2; ++qi)
    #pragma unroll
    for (int ds = 0; ds < 2; ++ds)
      qf[qi][ds] = *reinterpret_cast<const bf16x8*>(
          Qh + (size_t)(q0 + qi*16 + fr) * DHD + ds*32 + fg*8);

  f32x4 o[2][4] = {};
  float lsum[2] = {0.f, 0.f};           // per-lane partial row sums

  bf16x8 kf[2][2];
  auto loadK = [&](int kb) {
    #pragma unroll
    for (int ki = 0; ki < 2; ++ki)
      #pragma unroll
      for (int ds = 0; ds < 2; ++ds)
        kf[ki][ds] = *reinterpret_cast<const bf16x8*>(
            Kh + (size_t)(kb + ki*16 + fr) * DHD + ds*32 + fg*8);
  };
  loadK(s0 * 32);

  const int base = (lane & 48) + ((lane & 48) >> 2);

  auto block_step = [&](int kb, bool masked, bool pref) {
    f32x4 s[2][2] = {};
    __builtin_amdgcn_s_setprio(1);
    #pragma unroll
    for (int ds = 0; ds < 2; ++ds)
      #pragma unroll
      for (int ki = 0; ki < 2; ++ki)
        #pragma unroll
        for (int qi = 0; qi < 2; ++qi)
          s[ki][qi] = __builtin_amdgcn_mfma_f32_16x16x32_bf16(kf[ki][ds], qf[qi][ds], s[ki][qi], 0, 0, 0);
    __builtin_amdgcn_s_setprio(0);

    if (pref) loadK(kb + 32);

    bf16x8 vf[4];
    #pragma unroll
    for (int di = 0; di < 4; ++di)
      vf[di] = *reinterpret_cast<const bf16x8*>(
          Vh + (size_t)(di*16 + fr) * S_LEN + kb + fg*8);

    // p = exp(s) (no max subtraction: s >= 0, bounded); masked entries -> 0
    float p[2][2][4];
    #pragma unroll
    for (int ki = 0; ki < 2; ++ki)
      #pragma unroll
      for (int qi = 0; qi < 2; ++qi)
        #pragma unroll
        for (int r = 0; r < 4; ++r) {
          float e = __expf(s[ki][qi][r]);
          if (masked) {
            int kl = ki*16 + fg*4 + r, ql = qi*16 + fr;
            if (kl > ql) e = 0.f;
          }
          p[ki][qi][r] = e;
          lsum[qi] += e;
        }

    // pack P -> LDS, re-read as PV A-frag
    #pragma unroll
    for (int qi = 0; qi < 2; ++qi)
      #pragma unroll
      for (int ki = 0; ki < 2; ++ki) {
        uint2 wv;
        wv.x = pkbf(p[ki][qi][0], p[ki][qi][1]);
        wv.y = pkbf(p[ki][qi][2], p[ki][qi][3]);
        *reinterpret_cast<uint2*>(&Pt[qi*16 + fr][ki*16 + fg*4]) = wv;
      }
    asm volatile("s_waitcnt lgkmcnt(0)" ::: "memory");
    bf16x8 pf[2];
    #pragma unroll
    for (int qi = 0; qi < 2; ++qi)
      pf[qi] = *reinterpret_cast<const bf16x8*>(&Pt[qi*16 + fr][fg*8]);

    __builtin_amdgcn_s_setprio(1);
    #pragma unroll
    for (int qi = 0; qi < 2; ++qi)
      #pragma unroll
      for (int di = 0; di < 4; ++di)
        o[qi][di] = __builtin_amdgcn_mfma_f32_16x16x32_bf16(pf[qi], vf[di], o[qi][di], 0, 0, 0);
    __builtin_amdgcn_s_setprio(0);
  };

  for (int s = s0; s < s1; ++s)
    block_step(s * 32, s == tile, s + 1 < s1);

  // row sums (single reduce at end)
  float l_s[2];
  #pragma unroll
  for (int qi = 0; qi < 2; ++qi) {
    float r2 = lsum[qi];
    r2 += __shfl_xor(r2, 16);
    r2 += __shfl_xor(r2, 32);
    l_s[qi] = r2;
  }

  if (nc == 1) {
    const int b = bh >> 3, h = bh & 7;
    #pragma unroll
    for (int rr = 0; rr < 4; ++rr) {
      float l0 = __shfl(l_s[0], base + rr);
      float l1 = __shfl(l_s[1], base + rr);
      float i0 = 1.0f / l0, i1 = 1.0f / l1;
      int qa = q0 + fg*4 + rr;
      int qb2 = qa + 16;
      #pragma unroll
      for (int di = 0; di < 4; ++di) {
        int dh = di*16 + fr;
        out[(((size_t)(h * NB + b)) * S_LEN + qa) * DHD + dh] = o[0][di][rr] * i0;
        out[(((size_t)(h * NB + b)) * S_LEN + qb2) * DHD + dh] = o[1][di][rr] * i1;
      }
    }
  } else {
    const size_t slot = ((size_t)bh * 48 + (tile - 16)) * 4 + chunk;
    u16* op = Opart + slot * 2048 + (size_t)lane * 32;
    #pragma unroll
    for (int qi = 0; qi < 2; ++qi)
      #pragma unroll
      for (int di = 0; di < 4; ++di) {
        u16x4 v4;
        #pragma unroll
        for (int r = 0; r < 4; ++r) v4[r] = bfbits(o[qi][di][r]);
        *reinterpret_cast<u16x4*>(op + qi*16 + di*4) = v4;
      }
    if (fg == 0) {
      float* lp = lbuf + slot * 32;
      #pragma unroll
      for (int qi = 0; qi < 2; ++qi)
        lp[qi*16 + fr] = l_s[qi];
    }
  }
}

// ---------------------------------------------------------------------------
// Combine split-K partials for tiles 16..63: plain sums (no max weighting).
// ---------------------------------------------------------------------------
__launch_bounds__(64)
__global__ void reduce_kernel(const u16* __restrict__ Opart,
                              const float* __restrict__ lbuf,
                              float* __restrict__ out) {
  const int bid = blockIdx.x;           // 0..767
  const int bh = bid & 15;
  const int tile = 16 + (bid >> 4);
  const int nc = (tile >> 4) + 1;       // 2..4
  const int lane = threadIdx.x & 63;
  const int fr = lane & 15, fg = lane >> 4;

  float L[2][4] = {};
  f32x4 O[2][4] = {};

  const size_t slot0 = ((size_t)bh * 48 + (tile - 16)) * 4;
  for (int c = 0; c < nc; ++c) {
    const float* lp = lbuf + (slot0 + c) * 32;
    const u16* op = Opart + (slot0 + c) * 2048 + (size_t)lane * 32;
    #pragma unroll
    for (int qi = 0; qi < 2; ++qi) {
      #pragma unroll
      for (int r = 0; r < 4; ++r)
        L[qi][r] += lp[qi*16 + fg*4 + r];
      #pragma unroll
      for (int di = 0; di < 4; ++di) {
        u16x4 ov = *reinterpret_cast<const u16x4*>(op + qi*16 + di*4);
        #pragma unroll
        for (int r = 0; r < 4; ++r)
          O[qi][di][r] += bits2f(ov[r]);
      }
    }
  }

  const int b = bh >> 3, h = bh & 7;
  #pragma unroll
  for (int qi = 0; qi < 2; ++qi)
    #pragma unroll
    for (int r = 0; r < 4; ++r) {
      float inv = 1.0f / L[qi][r];
      int q = tile*32 + qi*16 + fg*4 + r;
      #pragma unroll
      for (int di = 0; di < 4; ++di)
        out[(((size_t)(h * NB + b)) * S_LEN + q) * DHD + di*16 + fr] = O[qi][di][r] * inv;
    }
}

extern "C" void kernel_launch(void* const* d_in, const int* in_sizes, int n_in,
                              void* d_out, int out_size, void* d_ws, size_t ws_size,
                              hipStream_t stream) {
  const float* q = (const float*)d_in[0];
  const float* k = (const float*)d_in[1];
  const float* v = (const float*)d_in[2];
  const float* W = (const float*)d_in[3];
  const float* b = (const float*)d_in[4];

  const size_t elems = (size_t)NB * NH * S_LEN * DHD;  // 2,097,152
  u16* Qw = (u16*)d_ws;
  u16* Kw = Qw + elems;
  u16* Vt = Kw + elems;
  u16* Xb = Vt + elems;                 // 4 * 2,097,152 u16 (q,k,v,W; W uses 262,144)
  // Opart overlaps Xb: Xb is consumed by proj_kernel before attn_kernel writes
  u16* Opart = Xb;                      // 3072 slots * 2048 u16 = 12 MiB
  float* lbuf = (float*)(Xb + 4 * elems);  // 3072 * 32 f32 = 384 KiB

  cvt_kernel<<<dim3(1024, 4), dim3(256), 0, stream>>>(q, k, v, W, Xb);

  proj_kernel<<<dim3(384), dim3(256), 0, stream>>>(Xb, Xb + 3 * elems, b, Qw, Kw, Vt);

  attn_kernel<<<dim3(4096), dim3(64), 0, stream>>>(Qw, Kw, Vt, Opart, lbuf, (float*)d_out);

  reduce_kernel<<<dim3(768), dim3(64), 0, stream>>>(Opart, lbuf, (float*)d_out);
}

// Round 5
// 84.358 us; speedup vs baseline: 1.7635x; 1.0148x over previous
//
#include <hip/hip_runtime.h>
#include <hip/hip_bf16.h>
#include <cstdint>
#include <cstddef>

typedef __bf16 bf16_t;
typedef bf16_t bf16x8 __attribute__((ext_vector_type(8)));
typedef float f32x4 __attribute__((ext_vector_type(4)));
typedef unsigned short u16;
typedef u16 u16x4 __attribute__((ext_vector_type(4)));
typedef u16 u16x8 __attribute__((ext_vector_type(8)));

#define S_LEN 2048
#define NB 2
#define NH 8
#define DHD 64
#define DM 512

// chunking: C = 10 steps of 32 KV rows per chunk
#define SLOTS_PER_BH 228   // sum over tiles>=10 of ceil((t+1)/10)

static __device__ __forceinline__ u16 bfbits(float f) {
  union { __bf16 h; u16 u; } c; c.h = (__bf16)f; return c.u;
}
static __device__ __forceinline__ float bits2f(u16 b) {
  union { u16 u; __bf16 h; } c; c.u = b; return (float)c.h;
}
static __device__ __forceinline__ uint32_t pkbf(float a, float b) {
  union { __bf16 h[2]; uint32_t u; } c;
  c.h[0] = (__bf16)a; c.h[1] = (__bf16)b;
  return c.u;
}
static __device__ __forceinline__ int slot_of(int bh, int tile, int chunk) {
  int g = tile / 10;                       // >= 1 for split tiles
  int soff = 5 * g * (g + 1) - 10;
  return bh * SLOTS_PER_BH + soff + (tile - 10 * g) * (g + 1) + chunk;
}

// ---------------------------------------------------------------------------
// fp32 -> bf16 convert pass (BW-bound). z picks {q,k,v,W}.
// ---------------------------------------------------------------------------
__launch_bounds__(256)
__global__ void cvt_kernel(const float* __restrict__ q, const float* __restrict__ k,
                           const float* __restrict__ v, const float* __restrict__ W,
                           u16* __restrict__ dst) {
  const int z = blockIdx.y;
  if (z == 3 && blockIdx.x >= 128) return;
  const float* __restrict__ src = (z == 0) ? q : (z == 1) ? k : (z == 2) ? v : W;
  u16* __restrict__ d = dst + (size_t)z * 2097152;
  size_t i = ((size_t)blockIdx.x * 256 + threadIdx.x) * 8;
  float4 a = *reinterpret_cast<const float4*>(src + i);
  float4 b = *reinterpret_cast<const float4*>(src + i + 4);
  u16x8 r;
  r[0] = bfbits(a.x); r[1] = bfbits(a.y); r[2] = bfbits(a.z); r[3] = bfbits(a.w);
  r[4] = bfbits(b.x); r[5] = bfbits(b.y); r[6] = bfbits(b.z); r[7] = bfbits(b.w);
  *reinterpret_cast<u16x8*>(d + i) = r;
}

// ---------------------------------------------------------------------------
// Projection GEMM (bf16 in): P = relu(X @ W^T + b).
// Q pre-scaled by 0.125*log2(e) so attention can use exp2 directly.
// Tile 128(M) x 64(N), 4 waves (each 64x32 quadrant, 4x2 frags).
// Grid 768 = 8 xcd * (8 n * 4 mi * 3 z) -> 3 blocks/CU.
// ---------------------------------------------------------------------------
__launch_bounds__(256)
__global__ void proj_kernel(const u16* __restrict__ Xall, const u16* __restrict__ Wb,
                            const float* __restrict__ bias,
                            u16* __restrict__ Qw, u16* __restrict__ Kw,
                            u16* __restrict__ Vt) {
  __shared__ u16 As[128][40];
  __shared__ u16 Bs[64][40];
  const int bid = blockIdx.x;
  const int xcd = bid & 7;
  const int u = bid >> 3;               // 0..95
  const int n0 = (u & 7) * 64;
  const int mi = (u >> 3) & 3;
  const int z = u >> 5;                 // 0..2
  const int m0 = (xcd * 4 + mi) * 128;
  const u16* __restrict__ X = Xall + (size_t)z * 2097152;

  const int t = threadIdx.x;
  const int lane = t & 63;
  const int wid = t >> 6;
  const int wr = wid >> 1, wc = wid & 1;
  const int fr = lane & 15, fg = lane >> 4;

  f32x4 acc[4][2] = {};

  const int arow0 = t >> 2, acol = (t & 3) * 8;   // A: 2 rounds of 64 rows
  const int brow = t >> 2, bcol = (t & 3) * 8;    // B: rows 0..63

  for (int k0 = 0; k0 < DM; k0 += 32) {
    *reinterpret_cast<uint4*>(&As[arow0][acol]) =
        *reinterpret_cast<const uint4*>(X + (size_t)(m0 + arow0) * DM + k0 + acol);
    *reinterpret_cast<uint4*>(&As[arow0 + 64][acol]) =
        *reinterpret_cast<const uint4*>(X + (size_t)(m0 + arow0 + 64) * DM + k0 + acol);
    *reinterpret_cast<uint4*>(&Bs[brow][bcol]) =
        *reinterpret_cast<const uint4*>(Wb + (size_t)(n0 + brow) * DM + k0 + bcol);
    __syncthreads();
    bf16x8 af[4], bfr[2];
    #pragma unroll
    for (int mi2 = 0; mi2 < 4; ++mi2)
      af[mi2] = *reinterpret_cast<const bf16x8*>(&As[wr*64 + mi2*16 + fr][fg*8]);
    #pragma unroll
    for (int ni = 0; ni < 2; ++ni)
      bfr[ni] = *reinterpret_cast<const bf16x8*>(&Bs[wc*32 + ni*16 + fr][fg*8]);
    __builtin_amdgcn_s_setprio(1);
    #pragma unroll
    for (int mi2 = 0; mi2 < 4; ++mi2)
      #pragma unroll
      for (int ni = 0; ni < 2; ++ni)
        acc[mi2][ni] = __builtin_amdgcn_mfma_f32_16x16x32_bf16(af[mi2], bfr[ni], acc[mi2][ni], 0, 0, 0);
    __builtin_amdgcn_s_setprio(0);
    __syncthreads();
  }

  const float QSCALE = 0.125f * 1.44269504089f;   // fold 1/sqrt(Dh) * log2(e)
  #pragma unroll
  for (int mi2 = 0; mi2 < 4; ++mi2) {
    #pragma unroll
    for (int ni = 0; ni < 2; ++ni) {
      #pragma unroll
      for (int r = 0; r < 4; ++r) {
        int m = m0 + wr*64 + mi2*16 + fg*4 + r;
        int e = n0 + wc*32 + ni*16 + fr;
        float v = acc[mi2][ni][r] + bias[e];
        if (z == 0) v *= QSCALE;
        v = fmaxf(v, 0.0f);
        u16 bv = bfbits(v);
        int b = m >> 11, s = m & (S_LEN - 1);
        int h = e >> 6, dh = e & 63;
        size_t bh = (size_t)(b * NH + h);
        if (z == 0)      Qw[(bh * S_LEN + s) * DHD + dh] = bv;
        else if (z == 1) Kw[(bh * S_LEN + s) * DHD + dh] = bv;
        else             Vt[(bh * DHD + dh) * S_LEN + s] = bv;
      }
    }
  }
}

// ---------------------------------------------------------------------------
// Split-K flash attention, unnormalized softmax p = exp2(s) (s >= 0, bounded,
// since Q,K are post-ReLU; log2e folded into Q). Uniform chunks of <=10
// 32-row steps -> 3808 equal-weight 1-wave blocks, no dead blocks.
// ---------------------------------------------------------------------------
__launch_bounds__(64)
__global__ void attn_kernel(const u16* __restrict__ Qw, const u16* __restrict__ Kw,
                            const u16* __restrict__ Vt, u16* __restrict__ Opart,
                            float* __restrict__ lbuf, float* __restrict__ out) {
  __shared__ u16 Pt[32][40];
  const int bid = blockIdx.x;
  const int bh = bid & 15;              // xcd = bid&7 -> 2 heads per XCD
  const int j = 237 - (bid >> 4);       // 0..237, longest-first
  // group g: tiles 10g..10g+9 have g+1 chunks; cum offsets 5g(g+1)
  int g = 0;
  #pragma unroll
  for (int i = 1; i < 7; ++i) g += (j >= 5*i*(i+1)) ? 1 : 0;
  const int r0 = j - 5*g*(g+1);
  const int tile = 10*g + r0 / (g+1);
  const int chunk = r0 % (g+1);
  const int s0 = chunk * 10;
  const int e = (s0 + 10 < tile + 1) ? (s0 + 10) : (tile + 1);
  const int q0 = tile * 32;

  const int lane = threadIdx.x & 63;
  const int fr = lane & 15, fg = lane >> 4;

  const u16* __restrict__ Qh = Qw + (size_t)bh * S_LEN * DHD;
  const u16* __restrict__ Kh = Kw + (size_t)bh * S_LEN * DHD;
  const u16* __restrict__ Vh = Vt + (size_t)bh * DHD * S_LEN;

  bf16x8 qf[2][2];
  #pragma unroll
  for (int qi = 0; qi < 2; ++qi)
    #pragma unroll
    for (int ds = 0; ds < 2; ++ds)
      qf[qi][ds] = *reinterpret_cast<const bf16x8*>(
          Qh + (size_t)(q0 + qi*16 + fr) * DHD + ds*32 + fg*8);

  f32x4 o[2][4] = {};
  float lsum[2] = {0.f, 0.f};           // per-lane partial row sums

  bf16x8 kf[2][2];
  auto loadK = [&](int kb) {
    #pragma unroll
    for (int ki = 0; ki < 2; ++ki)
      #pragma unroll
      for (int ds = 0; ds < 2; ++ds)
        kf[ki][ds] = *reinterpret_cast<const bf16x8*>(
            Kh + (size_t)(kb + ki*16 + fr) * DHD + ds*32 + fg*8);
  };
  loadK(s0 * 32);

  const int base = (lane & 48) + ((lane & 48) >> 2);

  auto block_step = [&](int kb, bool masked, bool pref) {
    f32x4 s[2][2] = {};
    __builtin_amdgcn_s_setprio(1);
    #pragma unroll
    for (int ds = 0; ds < 2; ++ds)
      #pragma unroll
      for (int ki = 0; ki < 2; ++ki)
        #pragma unroll
        for (int qi = 0; qi < 2; ++qi)
          s[ki][qi] = __builtin_amdgcn_mfma_f32_16x16x32_bf16(kf[ki][ds], qf[qi][ds], s[ki][qi], 0, 0, 0);
    __builtin_amdgcn_s_setprio(0);

    if (pref) loadK(kb + 32);

    bf16x8 vf[4];
    #pragma unroll
    for (int di = 0; di < 4; ++di)
      vf[di] = *reinterpret_cast<const bf16x8*>(
          Vh + (size_t)(di*16 + fr) * S_LEN + kb + fg*8);

    // p = 2^s (log2e pre-folded); masked entries -> 0
    float p[2][2][4];
    #pragma unroll
    for (int ki = 0; ki < 2; ++ki)
      #pragma unroll
      for (int qi = 0; qi < 2; ++qi)
        #pragma unroll
        for (int r = 0; r < 4; ++r) {
          float ev = __builtin_amdgcn_exp2f(s[ki][qi][r]);
          if (masked) {
            int kl = ki*16 + fg*4 + r, ql = qi*16 + fr;
            if (kl > ql) ev = 0.f;
          }
          p[ki][qi][r] = ev;
          lsum[qi] += ev;
        }

    // pack P -> LDS, re-read as PV A-frag
    #pragma unroll
    for (int qi = 0; qi < 2; ++qi)
      #pragma unroll
      for (int ki = 0; ki < 2; ++ki) {
        uint2 wv;
        wv.x = pkbf(p[ki][qi][0], p[ki][qi][1]);
        wv.y = pkbf(p[ki][qi][2], p[ki][qi][3]);
        *reinterpret_cast<uint2*>(&Pt[qi*16 + fr][ki*16 + fg*4]) = wv;
      }
    asm volatile("s_waitcnt lgkmcnt(0)" ::: "memory");
    bf16x8 pf[2];
    #pragma unroll
    for (int qi = 0; qi < 2; ++qi)
      pf[qi] = *reinterpret_cast<const bf16x8*>(&Pt[qi*16 + fr][fg*8]);

    __builtin_amdgcn_s_setprio(1);
    #pragma unroll
    for (int qi = 0; qi < 2; ++qi)
      #pragma unroll
      for (int di = 0; di < 4; ++di)
        o[qi][di] = __builtin_amdgcn_mfma_f32_16x16x32_bf16(pf[qi], vf[di], o[qi][di], 0, 0, 0);
    __builtin_amdgcn_s_setprio(0);
  };

  for (int s = s0; s < e; ++s)
    block_step(s * 32, s == tile, s + 1 < e);

  // row sums (single reduce at end)
  float l_s[2];
  #pragma unroll
  for (int qi = 0; qi < 2; ++qi) {
    float r2 = lsum[qi];
    r2 += __shfl_xor(r2, 16);
    r2 += __shfl_xor(r2, 32);
    l_s[qi] = r2;
  }

  if (g == 0) {
    // single-chunk tile: direct normalized write
    const int b = bh >> 3, h = bh & 7;
    #pragma unroll
    for (int rr = 0; rr < 4; ++rr) {
      float l0 = __shfl(l_s[0], base + rr);
      float l1 = __shfl(l_s[1], base + rr);
      float i0 = 1.0f / l0, i1 = 1.0f / l1;
      int qa = q0 + fg*4 + rr;
      int qb2 = qa + 16;
      #pragma unroll
      for (int di = 0; di < 4; ++di) {
        int dh = di*16 + fr;
        out[(((size_t)(h * NB + b)) * S_LEN + qa) * DHD + dh] = o[0][di][rr] * i0;
        out[(((size_t)(h * NB + b)) * S_LEN + qb2) * DHD + dh] = o[1][di][rr] * i1;
      }
    }
  } else {
    const size_t slot = (size_t)slot_of(bh, tile, chunk);
    u16* op = Opart + slot * 2048 + (size_t)lane * 32;
    #pragma unroll
    for (int qi = 0; qi < 2; ++qi)
      #pragma unroll
      for (int di = 0; di < 4; ++di) {
        u16x4 v4;
        #pragma unroll
        for (int r = 0; r < 4; ++r) v4[r] = bfbits(o[qi][di][r]);
        *reinterpret_cast<u16x4*>(op + qi*16 + di*4) = v4;
      }
    if (fg == 0) {
      float* lp = lbuf + slot * 32;
      #pragma unroll
      for (int qi = 0; qi < 2; ++qi)
        lp[qi*16 + fr] = l_s[qi];
    }
  }
}

// ---------------------------------------------------------------------------
// Combine split-K partials for tiles 10..63: plain sums.
// ---------------------------------------------------------------------------
__launch_bounds__(64)
__global__ void reduce_kernel(const u16* __restrict__ Opart,
                              const float* __restrict__ lbuf,
                              float* __restrict__ out) {
  const int bid = blockIdx.x;           // 0..863
  const int bh = bid & 15;
  const int tile = 10 + (bid >> 4);     // 10..63
  const int nc = tile / 10 + 1;         // 2..7
  const int lane = threadIdx.x & 63;
  const int fr = lane & 15, fg = lane >> 4;

  float L[2][4] = {};
  f32x4 O[2][4] = {};

  const int slot0 = slot_of(bh, tile, 0);
  for (int c = 0; c < nc; ++c) {
    const float* lp = lbuf + (size_t)(slot0 + c) * 32;
    const u16* op = Opart + (size_t)(slot0 + c) * 2048 + (size_t)lane * 32;
    #pragma unroll
    for (int qi = 0; qi < 2; ++qi) {
      #pragma unroll
      for (int r = 0; r < 4; ++r)
        L[qi][r] += lp[qi*16 + fg*4 + r];
      #pragma unroll
      for (int di = 0; di < 4; ++di) {
        u16x4 ov = *reinterpret_cast<const u16x4*>(op + qi*16 + di*4);
        #pragma unroll
        for (int r = 0; r < 4; ++r)
          O[qi][di][r] += bits2f(ov[r]);
      }
    }
  }

  const int b = bh >> 3, h = bh & 7;
  #pragma unroll
  for (int qi = 0; qi < 2; ++qi)
    #pragma unroll
    for (int r = 0; r < 4; ++r) {
      float inv = 1.0f / L[qi][r];
      int q = tile*32 + qi*16 + fg*4 + r;
      #pragma unroll
      for (int di = 0; di < 4; ++di)
        out[(((size_t)(h * NB + b)) * S_LEN + q) * DHD + di*16 + fr] = O[qi][di][r] * inv;
    }
}

extern "C" void kernel_launch(void* const* d_in, const int* in_sizes, int n_in,
                              void* d_out, int out_size, void* d_ws, size_t ws_size,
                              hipStream_t stream) {
  const float* q = (const float*)d_in[0];
  const float* k = (const float*)d_in[1];
  const float* v = (const float*)d_in[2];
  const float* W = (const float*)d_in[3];
  const float* b = (const float*)d_in[4];

  const size_t elems = (size_t)NB * NH * S_LEN * DHD;  // 2,097,152
  u16* Qw = (u16*)d_ws;
  u16* Kw = Qw + elems;
  u16* Vt = Kw + elems;
  u16* Xb = Vt + elems;                 // 4 * elems u16 = 16 MiB (q,k,v,W)
  // Opart overlaps Xb (Xb consumed by proj before attn writes partials):
  // 3648 slots * 2048 u16 = 14.25 MiB < 16 MiB
  u16* Opart = Xb;
  float* lbuf = (float*)(Xb + 4 * elems);  // 3648 * 32 f32 = 456 KiB

  cvt_kernel<<<dim3(1024, 4), dim3(256), 0, stream>>>(q, k, v, W, Xb);

  proj_kernel<<<dim3(768), dim3(256), 0, stream>>>(Xb, Xb + 3 * elems, b, Qw, Kw, Vt);

  attn_kernel<<<dim3(16 * 238), dim3(64), 0, stream>>>(Qw, Kw, Vt, Opart, lbuf, (float*)d_out);

  reduce_kernel<<<dim3(16 * 54), dim3(64), 0, stream>>>(Opart, lbuf, (float*)d_out);
}